// Round 13
// baseline (214.016 us; speedup 1.0000x reference)
//
#include <hip/hip_runtime.h>
#include <math.h>

// Problem constants
#define TOKENS 32768
#define DM 4096
#define NE 64
#define BALW 0.1f

#define TG 64
#define GBLOCKS (TOKENS / TG)  // 512

typedef __attribute__((ext_vector_type(8))) short short8;   // 8 bf16 = 4 VGPR
typedef __attribute__((ext_vector_type(4))) float f32x4;    // MFMA acc / nt-load

typedef unsigned short us;

// ---- RNE fp32 -> 3x bf16 split (B-prep only; runs once) ----
__device__ inline us bf16r(float f) {
  const unsigned u = __float_as_uint(f);
  return (us)((u + 0x7FFFu + ((u >> 16) & 1u)) >> 16);
}
__device__ inline float bf16f(us s) {
  return __uint_as_float(((unsigned)s) << 16);
}
__device__ inline void split8(const float4 v0, const float4 v1, short8& H,
                              short8& M, short8& L) {
  float v[8] = {v0.x, v0.y, v0.z, v0.w, v1.x, v1.y, v1.z, v1.w};
#pragma unroll
  for (int j = 0; j < 8; ++j) {
    const us hs = bf16r(v[j]);
    const float r1 = v[j] - bf16f(hs);  // exact (Sterbenz)
    const us ms = bf16r(r1);
    const float r2 = r1 - bf16f(ms);    // exact
    const us ls = bf16r(r2);
    H[j] = (short)hs; M[j] = (short)ms; L[j] = (short)ls;
  }
}

// ---- truncation fp32 -> 3x bf16 split (hot path; ext-vector operands) ----
__device__ inline void split8t(const f32x4 v0, const f32x4 v1, short8& H,
                               short8& M, short8& L) {
  unsigned u[8], um[8], ul[8];
  const float v[8] = {v0[0], v0[1], v0[2], v0[3], v1[0], v1[1], v1[2], v1[3]};
#pragma unroll
  for (int j = 0; j < 8; ++j) {
    u[j] = __float_as_uint(v[j]);
    const float r1 = v[j] - __uint_as_float(u[j] & 0xFFFF0000u);
    um[j] = __float_as_uint(r1);
    const float r2 = r1 - __uint_as_float(um[j] & 0xFFFF0000u);
    ul[j] = __float_as_uint(r2);
  }
  union Cvt { unsigned u4[4]; short8 s8; } h, m, l;
#pragma unroll
  for (int d = 0; d < 4; ++d) {
    h.u4[d] = __builtin_amdgcn_perm(u[2 * d + 1], u[2 * d], 0x07060302u);
    m.u4[d] = __builtin_amdgcn_perm(um[2 * d + 1], um[2 * d], 0x07060302u);
    l.u4[d] = __builtin_amdgcn_perm(ul[2 * d + 1], ul[2 * d], 0x07060302u);
  }
  H = h.s8; M = m.s8; L = l.s8;
}

#define MFMA(a, b, c) __builtin_amdgcn_mfma_f32_16x16x32_bf16(a, b, c, 0, 0, 0)

// ================= Kernel P: pre-split w1 into MFMA B-frag order =============
__global__ void prep_w1_kernel(const float* __restrict__ w1,
                               us* __restrict__ bws) {
  const int kc = blockIdx.x;       // 0..127
  const int tid = threadIdx.x;     // 256
  const int ns = tid >> 6;
  const int l = tid & 63;
  const int r = l & 15, g = l >> 4;
  const int n = 16 * ns + r;
  const int kb = 32 * kc + 8 * g;
  const float* src = &w1[(size_t)n * DM + kb];
  const float4 v0 = *reinterpret_cast<const float4*>(src);
  const float4 v1 = *reinterpret_cast<const float4*>(src + 4);
  short8 H, M, L;
  split8(v0, v1, H, M, L);
  us* dst = bws + ((size_t)(kc * 4 + ns) * 3) * 512 + l * 8;
  *reinterpret_cast<short8*>(dst) = H;
  *reinterpret_cast<short8*>(dst + 512) = M;
  *reinterpret_cast<short8*>(dst + 1024) = L;
}

// ================= Kernel A (primary): MFMA bf16x3 GEMM, 6-term ==============
// R7 proven structure (202.3/200.8 us) + three orthogonal micro-levers:
// (1) NON-TEMPORAL A loads (ext-vector type; the builtin rejects
//     HIP_vector_type): x is single-use (512 MB) -- nt keeps the x stream
//     from evicting the L2-resident B planes (1.5 MB, re-read every iter by
//     every CU). B latency, not B volume, is the suspect (R8/R10: volume
//     changes null/negative).
// (2) A-prefetch depth 2: two full iterations of HBM-latency cover.
// (3) s_setprio(1) around MFMA clusters (T5): barrier-free waves drift into
//     different phases -- the independent-wave regime where setprio measured
//     +4-7% (m191-analog), unlike lockstep GEMM (m190 null).
#define TMM 128

#define NTLOAD(p) __builtin_nontemporal_load(reinterpret_cast<const f32x4*>(p))

template <int SK>
__global__ __launch_bounds__(256, 2) void gemm_mfma_kernel(
    const float* __restrict__ x, const us* __restrict__ bws,
    float* __restrict__ hp) {
  constexpr int KS = DM / SK;
  constexpr int NIT = KS / 32;
  const int tid = threadIdx.x;
  const int kz = blockIdx.x % SK;
  const int mb = blockIdx.x / SK;
  const int w = tid >> 6;
  const int l = tid & 63;
  const int r = l & 15, g = l >> 4;
  const int row0 = mb * TMM + w * 32;
  const int kb0 = kz * KS;

  f32x4 acc[2][4];
#pragma unroll
  for (int i = 0; i < 2; ++i)
#pragma unroll
    for (int j = 0; j < 4; ++j) acc[i][j] = (f32x4)(0.f);

  const float* xA0 = &x[(size_t)(row0 + r) * DM + kb0 + 8 * g];
  const float* xA1 = xA0 + (size_t)16 * DM;
  const us* bb = bws + (size_t)(kb0 / 32) * 12 * 512 + l * 8;

  // prologue: A for iterations 0 and 1 (depth-2 pipeline); B for iteration 0
  f32x4 a00 = NTLOAD(xA0), a01 = NTLOAD(xA0 + 4);
  f32x4 a10 = NTLOAD(xA1), a11 = NTLOAD(xA1 + 4);
  f32x4 p00 = NTLOAD(xA0 + 32), p01 = NTLOAD(xA0 + 36);
  f32x4 p10 = NTLOAD(xA1 + 32), p11 = NTLOAD(xA1 + 36);
  short8 bf[4][3];
#pragma unroll
  for (int ns = 0; ns < 4; ++ns)
#pragma unroll
    for (int p = 0; p < 3; ++p)
      bf[ns][p] = *reinterpret_cast<const short8*>(bb + (ns * 3 + p) * 512);

  for (int it = 0; it < NIT; ++it) {
    const int itn = (it + 1 < NIT) ? it + 1 : it;       // B prefetch target
    const int it2 = (it + 2 < NIT) ? it + 2 : NIT - 1;  // A prefetch target
    const us* btn = bb + (size_t)itn * 12 * 512;
    const int ko2 = it2 * 32;
    // A prefetch for iter it+2 (two-iteration cover)
    const f32x4 q00 = NTLOAD(xA0 + ko2), q01 = NTLOAD(xA0 + ko2 + 4);
    const f32x4 q10 = NTLOAD(xA1 + ko2), q11 = NTLOAD(xA1 + ko2 + 4);

    short8 ah0, am0, al0, ah1, am1, al1;
    split8t(a00, a01, ah0, am0, al0);
    split8t(a10, a11, ah1, am1, al1);

#define PROW2(AH0, AH1, P)                                               \
  do {                                                                   \
    _Pragma("unroll") for (int ns = 0; ns < 4; ++ns) {                   \
      acc[0][ns] = MFMA(AH0, bf[ns][P], acc[0][ns]);                     \
      acc[1][ns] = MFMA(AH1, bf[ns][P], acc[1][ns]);                     \
    }                                                                    \
  } while (0)
#define RELOAD(P)                                                        \
  do {                                                                   \
    _Pragma("unroll") for (int ns = 0; ns < 4; ++ns) bf[ns][P] =         \
        *reinterpret_cast<const short8*>(btn + (ns * 3 + (P)) * 512);    \
  } while (0)

    // plane 0 (b_h): terms hh, mh, lh
    __builtin_amdgcn_s_setprio(1);
    PROW2(ah0, ah1, 0);
    PROW2(am0, am1, 0);
    PROW2(al0, al1, 0);
    __builtin_amdgcn_s_setprio(0);
    RELOAD(0);
    // plane 1 (b_m): terms hm, mm
    __builtin_amdgcn_s_setprio(1);
    PROW2(ah0, ah1, 1);
    PROW2(am0, am1, 1);
    __builtin_amdgcn_s_setprio(0);
    RELOAD(1);
    // plane 2 (b_l): term hl   (ml, lm, ll dropped: ~2^-24 rel)
    __builtin_amdgcn_s_setprio(1);
    PROW2(ah0, ah1, 2);
    __builtin_amdgcn_s_setprio(0);
    RELOAD(2);
#undef PROW2
#undef RELOAD

    // rotate A pipeline: cur <- nx1 <- nx2
    a00 = p00; a01 = p01; a10 = p10; a11 = p11;
    p00 = q00; p01 = q01; p10 = q10; p11 = q11;
  }

  // C/D layout: col = lane&15 (expert), row = 4*(lane>>4) + reg (token)
  float* dst = hp + (size_t)kz * TOKENS * NE;
#pragma unroll
  for (int ms = 0; ms < 2; ++ms)
#pragma unroll
    for (int ns = 0; ns < 4; ++ns)
#pragma unroll
      for (int q = 0; q < 4; ++q)
        dst[(size_t)(row0 + 16 * ms + 4 * g + q) * NE + 16 * ns + r] =
            acc[ms][ns][q];
}

// ================= Kernel A (fallback, proven fp32): 128x64, 4x8/thread =====
#define TM 128
#define BK 32
#define LDSA 132
#define LDSB 68

template <int SK>
__global__ __launch_bounds__(256, 4) void gemm_fp32_kernel(
    const float* __restrict__ x, const float* __restrict__ w1,
    float* __restrict__ hp) {
  constexpr int KS = DM / SK;
  __shared__ float As[BK * LDSA];
  __shared__ float Ws[BK * LDSB];
  const int tid = threadIdx.x;
  const int kz = blockIdx.x % SK;
  const int mb = blockIdx.x / SK;
  const int row0 = mb * TM;
  const int kbase = kz * KS;
  const int m0 = (tid >> 3) * 4;
  const int n0 = (tid & 7) * 8;
  const int rS = tid >> 2;
  const int kS = (tid & 3) * 4;

  float acc[4][8];
#pragma unroll
  for (int i = 0; i < 4; ++i)
#pragma unroll
    for (int j = 0; j < 8; ++j) acc[i][j] = 0.f;

  float4 ra[4], rw[2];
  const float* xp = &x[(size_t)(row0 + rS) * DM + kS];
  const float* wp = &w1[(size_t)rS * DM + kS];

#define LOAD_TILE(KC)                                                   \
  do {                                                                  \
    ra[0] = *reinterpret_cast<const float4*>(xp + (KC));                \
    ra[1] = *reinterpret_cast<const float4*>(xp + (KC) + 16);           \
    ra[2] = *reinterpret_cast<const float4*>(xp + (size_t)64 * DM + (KC));\
    ra[3] = *reinterpret_cast<const float4*>(xp + (size_t)64 * DM + (KC) + 16);\
    rw[0] = *reinterpret_cast<const float4*>(wp + (KC));                \
    rw[1] = *reinterpret_cast<const float4*>(wp + (KC) + 16);           \
  } while (0)

#define ST4(arr, stride, krow, col, v)                                  \
  do {                                                                  \
    arr[((krow) + 0) * (stride) + (col)] = (v).x;                       \
    arr[((krow) + 1) * (stride) + (col)] = (v).y;                       \
    arr[((krow) + 2) * (stride) + (col)] = (v).z;                       \
    arr[((krow) + 3) * (stride) + (col)] = (v).w;                       \
  } while (0)

#define STORE_TILE()                                                    \
  do {                                                                  \
    ST4(As, LDSA, kS, rS, ra[0]);                                       \
    ST4(As, LDSA, kS + 16, rS, ra[1]);                                  \
    ST4(As, LDSA, kS, rS + 64, ra[2]);                                  \
    ST4(As, LDSA, kS + 16, rS + 64, ra[3]);                             \
    ST4(Ws, LDSB, kS, rS, rw[0]);                                       \
    ST4(Ws, LDSB, kS + 16, rS, rw[1]);                                  \
  } while (0)

  LOAD_TILE(kbase);

  for (int kc = kbase; kc < kbase + KS; kc += BK) {
    __syncthreads();
    STORE_TILE();
    __syncthreads();
    if (kc + BK < kbase + KS) LOAD_TILE(kc + BK);
#pragma unroll 8
    for (int k = 0; k < BK; ++k) {
      const float4 a0 = *reinterpret_cast<const float4*>(&As[k * LDSA + m0]);
      const float4 b0 = *reinterpret_cast<const float4*>(&Ws[k * LDSB + n0]);
      const float4 b1 =
          *reinterpret_cast<const float4*>(&Ws[k * LDSB + n0 + 4]);
      const float a[4] = {a0.x, a0.y, a0.z, a0.w};
      const float b[8] = {b0.x, b0.y, b0.z, b0.w, b1.x, b1.y, b1.z, b1.w};
#pragma unroll
      for (int i = 0; i < 4; ++i)
#pragma unroll
        for (int j = 0; j < 8; ++j) acc[i][j] = fmaf(a[i], b[j], acc[i][j]);
    }
  }
#undef LOAD_TILE
#undef ST4
#undef STORE_TILE

  float* dst = hp + (size_t)kz * TOKENS * NE;
#pragma unroll
  for (int i = 0; i < 4; ++i) {
    const size_t o = (size_t)(row0 + m0 + i) * NE;
    *reinterpret_cast<float4*>(&dst[o + n0]) =
        make_float4(acc[i][0], acc[i][1], acc[i][2], acc[i][3]);
    *reinterpret_cast<float4*>(&dst[o + n0 + 4]) =
        make_float4(acc[i][4], acc[i][5], acc[i][6], acc[i][7]);
  }
}

// ================= Kernel B: gate (R7 proven version) =================
template <int SK>
__global__ __launch_bounds__(256) void gate_kernel(
    const float* __restrict__ hp, const float* __restrict__ w2,
    const float* __restrict__ noise, float* __restrict__ out_idx,
    float* __restrict__ out_score, float* __restrict__ imp_part,
    float* __restrict__ load_part) {
  __shared__ float hs[TG * 65];
  __shared__ float w2s[NE * 65];
  __shared__ float ls[TG * 66];
  __shared__ float csum[2 * NE];
  __shared__ int hist[NE];
  const int tid = threadIdx.x;
  const int t0 = blockIdx.x * TG;
  if (tid < NE) hist[tid] = 0;

#pragma unroll
  for (int it = 0; it < 4; ++it) {
    const int f = tid + 256 * it;
    const int c = f & 15;
    const int t = f >> 4;
    const size_t g = (size_t)(t0 + t) * NE + c * 4;
    float4 p = *reinterpret_cast<const float4*>(&hp[g]);
#pragma unroll
    for (int s = 1; s < SK; ++s) {
      const float4 q =
          *reinterpret_cast<const float4*>(&hp[(size_t)s * TOKENS * NE + g]);
      p.x += q.x; p.y += q.y; p.z += q.z; p.w += q.w;
    }
    float* d = &hs[t * 65 + c * 4];
    d[0] = tanhf(p.x);
    d[1] = tanhf(p.y);
    d[2] = tanhf(p.z);
    d[3] = tanhf(p.w);
  }
#pragma unroll
  for (int it = 0; it < 4; ++it) {
    const int f = tid + 256 * it;
    const int c = f & 15;
    const int rr = f >> 4;
    const float4 v =
        *reinterpret_cast<const float4*>(&w2[(size_t)rr * NE + c * 4]);
    float* d = &w2s[rr * 65 + c * 4];
    d[0] = v.x; d[1] = v.y; d[2] = v.z; d[3] = v.w;
  }
  __syncthreads();

  {
    const int m0 = (tid >> 4) * 4;
    const int n0 = (tid & 15) * 4;
    float acc[4][4];
#pragma unroll
    for (int i = 0; i < 4; ++i)
#pragma unroll
      for (int j = 0; j < 4; ++j) acc[i][j] = 0.f;
#pragma unroll 8
    for (int k = 0; k < NE; ++k) {
      float a[4], b[4];
#pragma unroll
      for (int i = 0; i < 4; ++i) a[i] = hs[(m0 + i) * 65 + k];
#pragma unroll
      for (int j = 0; j < 4; ++j) b[j] = w2s[(n0 + j) * 65 + k];
#pragma unroll
      for (int i = 0; i < 4; ++i)
#pragma unroll
        for (int j = 0; j < 4; ++j) acc[i][j] = fmaf(a[i], b[j], acc[i][j]);
    }
#pragma unroll
    for (int i = 0; i < 4; ++i)
#pragma unroll
      for (int j = 0; j < 4; ++j) ls[(m0 + i) * 66 + n0 + j] = acc[i][j];
  }
  __syncthreads();

  if (tid < TG) {
    const int t = tid;
    float mx = -INFINITY, best = -INFINITY;
    int bi = 0;
    for (int e = 0; e < NE; ++e) {
      const float lv = ls[t * 66 + e];
      mx = fmaxf(mx, lv);
      const float gg = lv + noise[(size_t)(t0 + t) * NE + e];
      if (gg > best) { best = gg; bi = e; }
    }
    float s = 0.f;
    for (int e = 0; e < NE; ++e) {
      const float ex = expf(ls[t * 66 + e] - mx);
      s += ex;
      ls[t * 66 + e] = ex;
    }
    const float inv = 1.f / s;
    for (int e = 0; e < NE; ++e) ls[t * 66 + e] *= inv;
    out_idx[t0 + t] = (float)bi;
    out_score[t0 + t] = best;
    atomicAdd(&hist[bi], 1);
  }
  __syncthreads();

  if (tid < 128) {
    const int e = tid & 63;
    const int half = tid >> 6;
    float s = 0.f;
    for (int rr = half * 32; rr < half * 32 + 32; ++rr) s += ls[rr * 66 + e];
    csum[half * NE + e] = s;
  }
  __syncthreads();
  if (tid < NE) {
    imp_part[(size_t)blockIdx.x * NE + tid] = csum[tid] + csum[NE + tid];
    load_part[(size_t)blockIdx.x * NE + tid] = (float)hist[tid];
  }
}

// ================= Kernel C: finalize (1024 threads, 16-way; proven) ========
__global__ void finalize_kernel(const float* __restrict__ imp_part,
                                const float* __restrict__ load_part,
                                float* __restrict__ out) {
  __shared__ float si[16][NE];
  __shared__ float sl[16][NE];
  const int tid = threadIdx.x;   // 0..1023
  const int e = tid & 63;
  const int seg = tid >> 6;      // 0..15
  float imp = 0.f, ld = 0.f;
  for (int b = seg; b < GBLOCKS; b += 16) {
    imp += imp_part[(size_t)b * NE + e];
    ld += load_part[(size_t)b * NE + e];
  }
  si[seg][e] = imp;
  sl[seg][e] = ld;
  __syncthreads();
  if (tid < NE) {
    float ti = 0.f, tl = 0.f;
#pragma unroll
    for (int s = 0; s < 16; ++s) { ti += si[s][tid]; tl += sl[s][tid]; }
    const float imp_mean = ti / (float)TOKENS;
    const float load_mean = tl / (float)TOKENS;
    out[2 * TOKENS + 1 + tid] = load_mean;
    out[2 * TOKENS + 1 + NE + tid] = imp_mean;
    float prod = imp_mean * load_mean;
#pragma unroll
    for (int off = 32; off > 0; off >>= 1) prod += __shfl_down(prod, off);
    if (tid == 0) out[2 * TOKENS] = (float)NE * prod * BALW;
  }
}

// ================= launch =================
extern "C" void kernel_launch(void* const* d_in, const int* in_sizes, int n_in,
                              void* d_out, int out_size, void* d_ws,
                              size_t ws_size, hipStream_t stream) {
  const float* x = (const float*)d_in[0];
  const float* w1 = (const float*)d_in[1];
  const float* w2 = (const float*)d_in[2];
  const float* noise = (const float*)d_in[3];
  float* out = (float*)d_out;

  const size_t bws_shorts = (size_t)128 * 4 * 3 * 512;  // 786432 (1.5 MB)
  const size_t part_elems = (size_t)2 * GBLOCKS * NE;
  const size_t need_mfma = bws_shorts * sizeof(us) +
                           ((size_t)2 * TOKENS * NE + part_elems) *
                               sizeof(float);  // ~18.6 MB
  const size_t need_fp32 =
      ((size_t)2 * TOKENS * NE + part_elems) * sizeof(float);  // ~17 MB

  if (ws_size == 0 || ws_size >= need_mfma) {
    us* bws = (us*)d_ws;
    float* hp = (float*)(bws + bws_shorts);
    float* imp_part = hp + (size_t)2 * TOKENS * NE;
    float* load_part = imp_part + (size_t)GBLOCKS * NE;
    hipLaunchKernelGGL(prep_w1_kernel, dim3(128), dim3(256), 0, stream, w1,
                       bws);
    hipLaunchKernelGGL((gemm_mfma_kernel<2>), dim3((TOKENS / TMM) * 2),
                       dim3(256), 0, stream, x, bws, hp);
    hipLaunchKernelGGL((gate_kernel<2>), dim3(GBLOCKS), dim3(256), 0, stream,
                       hp, w2, noise, out, out + TOKENS, imp_part, load_part);
    hipLaunchKernelGGL(finalize_kernel, dim3(1), dim3(1024), 0, stream,
                       imp_part, load_part, out);
  } else if (ws_size >= need_fp32) {
    float* hp = (float*)d_ws;
    float* imp_part = hp + (size_t)2 * TOKENS * NE;
    float* load_part = imp_part + (size_t)GBLOCKS * NE;
    hipLaunchKernelGGL((gemm_fp32_kernel<2>), dim3((TOKENS / TM) * 2),
                       dim3(256), 0, stream, x, w1, hp);
    hipLaunchKernelGGL((gate_kernel<2>), dim3(GBLOCKS), dim3(256), 0, stream,
                       hp, w2, noise, out, out + TOKENS, imp_part, load_part);
    hipLaunchKernelGGL(finalize_kernel, dim3(1), dim3(1024), 0, stream,
                       imp_part, load_part, out);
  }
}

// Round 14
// 200.240 us; speedup vs baseline: 1.0688x; 1.0688x over previous
//
#include <hip/hip_runtime.h>
#include <math.h>

// Problem constants
#define TOKENS 32768
#define DM 4096
#define NE 64
#define BALW 0.1f

#define TG 64
#define GBLOCKS (TOKENS / TG)  // 512

typedef __attribute__((ext_vector_type(8))) short short8;   // 8 bf16 = 4 VGPR
typedef __attribute__((ext_vector_type(4))) float f32x4;    // MFMA acc

typedef unsigned short us;

// ---- RNE fp32 -> 3x bf16 split (B-prep only; runs once) ----
__device__ inline us bf16r(float f) {
  const unsigned u = __float_as_uint(f);
  return (us)((u + 0x7FFFu + ((u >> 16) & 1u)) >> 16);
}
__device__ inline float bf16f(us s) {
  return __uint_as_float(((unsigned)s) << 16);
}
__device__ inline void split8(const float4 v0, const float4 v1, short8& H,
                              short8& M, short8& L) {
  float v[8] = {v0.x, v0.y, v0.z, v0.w, v1.x, v1.y, v1.z, v1.w};
#pragma unroll
  for (int j = 0; j < 8; ++j) {
    const us hs = bf16r(v[j]);
    const float r1 = v[j] - bf16f(hs);  // exact (Sterbenz)
    const us ms = bf16r(r1);
    const float r2 = r1 - bf16f(ms);    // exact
    const us ls = bf16r(r2);
    H[j] = (short)hs; M[j] = (short)ms; L[j] = (short)ls;
  }
}

// ---- truncation fp32 -> 3x bf16 split (hot path: 44 VALU per 8 elems) ----
__device__ inline void split8t(const float4 v0, const float4 v1, short8& H,
                               short8& M, short8& L) {
  unsigned u[8], um[8], ul[8];
  const float v[8] = {v0.x, v0.y, v0.z, v0.w, v1.x, v1.y, v1.z, v1.w};
#pragma unroll
  for (int j = 0; j < 8; ++j) {
    u[j] = __float_as_uint(v[j]);
    const float r1 = v[j] - __uint_as_float(u[j] & 0xFFFF0000u);
    um[j] = __float_as_uint(r1);
    const float r2 = r1 - __uint_as_float(um[j] & 0xFFFF0000u);
    ul[j] = __float_as_uint(r2);
  }
  union Cvt { unsigned u4[4]; short8 s8; } h, m, l;
#pragma unroll
  for (int d = 0; d < 4; ++d) {
    h.u4[d] = __builtin_amdgcn_perm(u[2 * d + 1], u[2 * d], 0x07060302u);
    m.u4[d] = __builtin_amdgcn_perm(um[2 * d + 1], um[2 * d], 0x07060302u);
    l.u4[d] = __builtin_amdgcn_perm(ul[2 * d + 1], ul[2 * d], 0x07060302u);
  }
  H = h.s8; M = m.s8; L = l.s8;
}

#define MFMA(a, b, c) __builtin_amdgcn_mfma_f32_16x16x32_bf16(a, b, c, 0, 0, 0)

// ================= Kernel P: pre-split w1 into MFMA B-frag order =============
__global__ void prep_w1_kernel(const float* __restrict__ w1,
                               us* __restrict__ bws) {
  const int kc = blockIdx.x;       // 0..127
  const int tid = threadIdx.x;     // 256
  const int ns = tid >> 6;
  const int l = tid & 63;
  const int r = l & 15, g = l >> 4;
  const int n = 16 * ns + r;
  const int kb = 32 * kc + 8 * g;
  const float* src = &w1[(size_t)n * DM + kb];
  const float4 v0 = *reinterpret_cast<const float4*>(src);
  const float4 v1 = *reinterpret_cast<const float4*>(src + 4);
  short8 H, M, L;
  split8(v0, v1, H, M, L);
  us* dst = bws + ((size_t)(kc * 4 + ns) * 3) * 512 + l * 8;
  *reinterpret_cast<short8*>(dst) = H;
  *reinterpret_cast<short8*>(dst + 512) = M;
  *reinterpret_cast<short8*>(dst + 1024) = L;
}

// ================= Kernel A (primary): MFMA bf16x3 GEMM, 6-term ==============
// PROVEN BEST (R11, 200.75 us): SK=2, grid = (TOKENS/128)*2 = 512 blocks,
// 4 waves each -> 2 blocks/CU, 2 waves/SIMD. Wave tile: 32 tokens x 64
// experts. No LDS, no barriers. 6 product terms (hh,hm,mh,mm,hl,lh);
// dropped ml+lm ~2^-24 rel. B planes reloaded in place after last consumer;
// A prefetched 1 iter ahead. Exhaustively measured local optimum -- every
// perturbation regressed: occupancy x2 (R10 +59us) / x0.5 (R8 +24us),
// B-traffic /2 (R8) or x2 (R10), LDS-staged A (R9 +111us), 1-barrier BK=16
// pipeline (R2 +56us), nt-loads+depth2+setprio (R13 +13us).
#define TMM 128

template <int SK>
__global__ __launch_bounds__(256, 2) void gemm_mfma_kernel(
    const float* __restrict__ x, const us* __restrict__ bws,
    float* __restrict__ hp) {
  constexpr int KS = DM / SK;
  constexpr int NIT = KS / 32;
  const int tid = threadIdx.x;
  const int kz = blockIdx.x % SK;
  const int mb = blockIdx.x / SK;
  const int w = tid >> 6;
  const int l = tid & 63;
  const int r = l & 15, g = l >> 4;
  const int row0 = mb * TMM + w * 32;
  const int kb0 = kz * KS;

  f32x4 acc[2][4];
#pragma unroll
  for (int i = 0; i < 2; ++i)
#pragma unroll
    for (int j = 0; j < 4; ++j) acc[i][j] = (f32x4)(0.f);

  const float* xA0 = &x[(size_t)(row0 + r) * DM + kb0 + 8 * g];
  const float* xA1 = xA0 + (size_t)16 * DM;
  const us* bb = bws + (size_t)(kb0 / 32) * 12 * 512 + l * 8;

  // prologue: A and B for iteration 0
  float4 a00 = *reinterpret_cast<const float4*>(xA0);
  float4 a01 = *reinterpret_cast<const float4*>(xA0 + 4);
  float4 a10 = *reinterpret_cast<const float4*>(xA1);
  float4 a11 = *reinterpret_cast<const float4*>(xA1 + 4);
  short8 bf[4][3];
#pragma unroll
  for (int ns = 0; ns < 4; ++ns)
#pragma unroll
    for (int p = 0; p < 3; ++p)
      bf[ns][p] = *reinterpret_cast<const short8*>(bb + (ns * 3 + p) * 512);

  for (int it = 0; it < NIT; ++it) {
    const int itn = (it + 1 < NIT) ? it + 1 : it;  // clamped (last redundant)
    const us* btn = bb + (size_t)itn * 12 * 512;
    const int ko = itn * 32;
    // A prefetch for next iter: full-iteration HBM cover
    const float4 n00 = *reinterpret_cast<const float4*>(xA0 + ko);
    const float4 n01 = *reinterpret_cast<const float4*>(xA0 + ko + 4);
    const float4 n10 = *reinterpret_cast<const float4*>(xA1 + ko);
    const float4 n11 = *reinterpret_cast<const float4*>(xA1 + ko + 4);

    short8 ah0, am0, al0, ah1, am1, al1;
    split8t(a00, a01, ah0, am0, al0);
    split8t(a10, a11, ah1, am1, al1);

#define PROW2(AH0, AH1, P)                                               \
  do {                                                                   \
    _Pragma("unroll") for (int ns = 0; ns < 4; ++ns) {                   \
      acc[0][ns] = MFMA(AH0, bf[ns][P], acc[0][ns]);                     \
      acc[1][ns] = MFMA(AH1, bf[ns][P], acc[1][ns]);                     \
    }                                                                    \
  } while (0)
#define RELOAD(P)                                                        \
  do {                                                                   \
    _Pragma("unroll") for (int ns = 0; ns < 4; ++ns) bf[ns][P] =         \
        *reinterpret_cast<const short8*>(btn + (ns * 3 + (P)) * 512);    \
  } while (0)

    // plane 0 (b_h): terms hh, mh, lh
    PROW2(ah0, ah1, 0);
    PROW2(am0, am1, 0);
    PROW2(al0, al1, 0);
    RELOAD(0);
    // plane 1 (b_m): terms hm, mm
    PROW2(ah0, ah1, 1);
    PROW2(am0, am1, 1);
    RELOAD(1);
    // plane 2 (b_l): term hl   (ml, lm, ll dropped: ~2^-24 rel)
    PROW2(ah0, ah1, 2);
    RELOAD(2);
#undef PROW2
#undef RELOAD

    a00 = n00; a01 = n01; a10 = n10; a11 = n11;
  }

  // C/D layout: col = lane&15 (expert), row = 4*(lane>>4) + reg (token)
  float* dst = hp + (size_t)kz * TOKENS * NE;
#pragma unroll
  for (int ms = 0; ms < 2; ++ms)
#pragma unroll
    for (int ns = 0; ns < 4; ++ns)
#pragma unroll
      for (int q = 0; q < 4; ++q)
        dst[(size_t)(row0 + 16 * ms + 4 * g + q) * NE + 16 * ns + r] =
            acc[ms][ns][q];
}

// ================= Kernel A (fallback, proven fp32): 128x64, 4x8/thread =====
#define TM 128
#define BK 32
#define LDSA 132
#define LDSB 68

template <int SK>
__global__ __launch_bounds__(256, 4) void gemm_fp32_kernel(
    const float* __restrict__ x, const float* __restrict__ w1,
    float* __restrict__ hp) {
  constexpr int KS = DM / SK;
  __shared__ float As[BK * LDSA];
  __shared__ float Ws[BK * LDSB];
  const int tid = threadIdx.x;
  const int kz = blockIdx.x % SK;
  const int mb = blockIdx.x / SK;
  const int row0 = mb * TM;
  const int kbase = kz * KS;
  const int m0 = (tid >> 3) * 4;
  const int n0 = (tid & 7) * 8;
  const int rS = tid >> 2;
  const int kS = (tid & 3) * 4;

  float acc[4][8];
#pragma unroll
  for (int i = 0; i < 4; ++i)
#pragma unroll
    for (int j = 0; j < 8; ++j) acc[i][j] = 0.f;

  float4 ra[4], rw[2];
  const float* xp = &x[(size_t)(row0 + rS) * DM + kS];
  const float* wp = &w1[(size_t)rS * DM + kS];

#define LOAD_TILE(KC)                                                   \
  do {                                                                  \
    ra[0] = *reinterpret_cast<const float4*>(xp + (KC));                \
    ra[1] = *reinterpret_cast<const float4*>(xp + (KC) + 16);           \
    ra[2] = *reinterpret_cast<const float4*>(xp + (size_t)64 * DM + (KC));\
    ra[3] = *reinterpret_cast<const float4*>(xp + (size_t)64 * DM + (KC) + 16);\
    rw[0] = *reinterpret_cast<const float4*>(wp + (KC));                \
    rw[1] = *reinterpret_cast<const float4*>(wp + (KC) + 16);           \
  } while (0)

#define ST4(arr, stride, krow, col, v)                                  \
  do {                                                                  \
    arr[((krow) + 0) * (stride) + (col)] = (v).x;                       \
    arr[((krow) + 1) * (stride) + (col)] = (v).y;                       \
    arr[((krow) + 2) * (stride) + (col)] = (v).z;                       \
    arr[((krow) + 3) * (stride) + (col)] = (v).w;                       \
  } while (0)

#define STORE_TILE()                                                    \
  do {                                                                  \
    ST4(As, LDSA, kS, rS, ra[0]);                                       \
    ST4(As, LDSA, kS + 16, rS, ra[1]);                                  \
    ST4(As, LDSA, kS, rS + 64, ra[2]);                                  \
    ST4(As, LDSA, kS + 16, rS + 64, ra[3]);                             \
    ST4(Ws, LDSB, kS, rS, rw[0]);                                       \
    ST4(Ws, LDSB, kS + 16, rS, rw[1]);                                  \
  } while (0)

  LOAD_TILE(kbase);

  for (int kc = kbase; kc < kbase + KS; kc += BK) {
    __syncthreads();
    STORE_TILE();
    __syncthreads();
    if (kc + BK < kbase + KS) LOAD_TILE(kc + BK);
#pragma unroll 8
    for (int k = 0; k < BK; ++k) {
      const float4 a0 = *reinterpret_cast<const float4*>(&As[k * LDSA + m0]);
      const float4 b0 = *reinterpret_cast<const float4*>(&Ws[k * LDSB + n0]);
      const float4 b1 =
          *reinterpret_cast<const float4*>(&Ws[k * LDSB + n0 + 4]);
      const float a[4] = {a0.x, a0.y, a0.z, a0.w};
      const float b[8] = {b0.x, b0.y, b0.z, b0.w, b1.x, b1.y, b1.z, b1.w};
#pragma unroll
      for (int i = 0; i < 4; ++i)
#pragma unroll
        for (int j = 0; j < 8; ++j) acc[i][j] = fmaf(a[i], b[j], acc[i][j]);
    }
  }
#undef LOAD_TILE
#undef ST4
#undef STORE_TILE

  float* dst = hp + (size_t)kz * TOKENS * NE;
#pragma unroll
  for (int i = 0; i < 4; ++i) {
    const size_t o = (size_t)(row0 + m0 + i) * NE;
    *reinterpret_cast<float4*>(&dst[o + n0]) =
        make_float4(acc[i][0], acc[i][1], acc[i][2], acc[i][3]);
    *reinterpret_cast<float4*>(&dst[o + n0 + 4]) =
        make_float4(acc[i][4], acc[i][5], acc[i][6], acc[i][7]);
  }
}

// ================= Kernel B: gate (R7 proven version) =================
template <int SK>
__global__ __launch_bounds__(256) void gate_kernel(
    const float* __restrict__ hp, const float* __restrict__ w2,
    const float* __restrict__ noise, float* __restrict__ out_idx,
    float* __restrict__ out_score, float* __restrict__ imp_part,
    float* __restrict__ load_part) {
  __shared__ float hs[TG * 65];
  __shared__ float w2s[NE * 65];
  __shared__ float ls[TG * 66];
  __shared__ float csum[2 * NE];
  __shared__ int hist[NE];
  const int tid = threadIdx.x;
  const int t0 = blockIdx.x * TG;
  if (tid < NE) hist[tid] = 0;

#pragma unroll
  for (int it = 0; it < 4; ++it) {
    const int f = tid + 256 * it;
    const int c = f & 15;
    const int t = f >> 4;
    const size_t g = (size_t)(t0 + t) * NE + c * 4;
    float4 p = *reinterpret_cast<const float4*>(&hp[g]);
#pragma unroll
    for (int s = 1; s < SK; ++s) {
      const float4 q =
          *reinterpret_cast<const float4*>(&hp[(size_t)s * TOKENS * NE + g]);
      p.x += q.x; p.y += q.y; p.z += q.z; p.w += q.w;
    }
    float* d = &hs[t * 65 + c * 4];
    d[0] = tanhf(p.x);
    d[1] = tanhf(p.y);
    d[2] = tanhf(p.z);
    d[3] = tanhf(p.w);
  }
#pragma unroll
  for (int it = 0; it < 4; ++it) {
    const int f = tid + 256 * it;
    const int c = f & 15;
    const int rr = f >> 4;
    const float4 v =
        *reinterpret_cast<const float4*>(&w2[(size_t)rr * NE + c * 4]);
    float* d = &w2s[rr * 65 + c * 4];
    d[0] = v.x; d[1] = v.y; d[2] = v.z; d[3] = v.w;
  }
  __syncthreads();

  {
    const int m0 = (tid >> 4) * 4;
    const int n0 = (tid & 15) * 4;
    float acc[4][4];
#pragma unroll
    for (int i = 0; i < 4; ++i)
#pragma unroll
      for (int j = 0; j < 4; ++j) acc[i][j] = 0.f;
#pragma unroll 8
    for (int k = 0; k < NE; ++k) {
      float a[4], b[4];
#pragma unroll
      for (int i = 0; i < 4; ++i) a[i] = hs[(m0 + i) * 65 + k];
#pragma unroll
      for (int j = 0; j < 4; ++j) b[j] = w2s[(n0 + j) * 65 + k];
#pragma unroll
      for (int i = 0; i < 4; ++i)
#pragma unroll
        for (int j = 0; j < 4; ++j) acc[i][j] = fmaf(a[i], b[j], acc[i][j]);
    }
#pragma unroll
    for (int i = 0; i < 4; ++i)
#pragma unroll
      for (int j = 0; j < 4; ++j) ls[(m0 + i) * 66 + n0 + j] = acc[i][j];
  }
  __syncthreads();

  if (tid < TG) {
    const int t = tid;
    float mx = -INFINITY, best = -INFINITY;
    int bi = 0;
    for (int e = 0; e < NE; ++e) {
      const float lv = ls[t * 66 + e];
      mx = fmaxf(mx, lv);
      const float gg = lv + noise[(size_t)(t0 + t) * NE + e];
      if (gg > best) { best = gg; bi = e; }
    }
    float s = 0.f;
    for (int e = 0; e < NE; ++e) {
      const float ex = expf(ls[t * 66 + e] - mx);
      s += ex;
      ls[t * 66 + e] = ex;
    }
    const float inv = 1.f / s;
    for (int e = 0; e < NE; ++e) ls[t * 66 + e] *= inv;
    out_idx[t0 + t] = (float)bi;
    out_score[t0 + t] = best;
    atomicAdd(&hist[bi], 1);
  }
  __syncthreads();

  if (tid < 128) {
    const int e = tid & 63;
    const int half = tid >> 6;
    float s = 0.f;
    for (int rr = half * 32; rr < half * 32 + 32; ++rr) s += ls[rr * 66 + e];
    csum[half * NE + e] = s;
  }
  __syncthreads();
  if (tid < NE) {
    imp_part[(size_t)blockIdx.x * NE + tid] = csum[tid] + csum[NE + tid];
    load_part[(size_t)blockIdx.x * NE + tid] = (float)hist[tid];
  }
}

// ================= Kernel C: finalize (1024 threads, 16-way; proven) ========
__global__ void finalize_kernel(const float* __restrict__ imp_part,
                                const float* __restrict__ load_part,
                                float* __restrict__ out) {
  __shared__ float si[16][NE];
  __shared__ float sl[16][NE];
  const int tid = threadIdx.x;   // 0..1023
  const int e = tid & 63;
  const int seg = tid >> 6;      // 0..15
  float imp = 0.f, ld = 0.f;
  for (int b = seg; b < GBLOCKS; b += 16) {
    imp += imp_part[(size_t)b * NE + e];
    ld += load_part[(size_t)b * NE + e];
  }
  si[seg][e] = imp;
  sl[seg][e] = ld;
  __syncthreads();
  if (tid < NE) {
    float ti = 0.f, tl = 0.f;
#pragma unroll
    for (int s = 0; s < 16; ++s) { ti += si[s][tid]; tl += sl[s][tid]; }
    const float imp_mean = ti / (float)TOKENS;
    const float load_mean = tl / (float)TOKENS;
    out[2 * TOKENS + 1 + tid] = load_mean;
    out[2 * TOKENS + 1 + NE + tid] = imp_mean;
    float prod = imp_mean * load_mean;
#pragma unroll
    for (int off = 32; off > 0; off >>= 1) prod += __shfl_down(prod, off);
    if (tid == 0) out[2 * TOKENS] = (float)NE * prod * BALW;
  }
}

// ================= launch =================
extern "C" void kernel_launch(void* const* d_in, const int* in_sizes, int n_in,
                              void* d_out, int out_size, void* d_ws,
                              size_t ws_size, hipStream_t stream) {
  const float* x = (const float*)d_in[0];
  const float* w1 = (const float*)d_in[1];
  const float* w2 = (const float*)d_in[2];
  const float* noise = (const float*)d_in[3];
  float* out = (float*)d_out;

  const size_t bws_shorts = (size_t)128 * 4 * 3 * 512;  // 786432 (1.5 MB)
  const size_t part_elems = (size_t)2 * GBLOCKS * NE;
  const size_t need_mfma = bws_shorts * sizeof(us) +
                           ((size_t)2 * TOKENS * NE + part_elems) *
                               sizeof(float);  // ~18.6 MB
  const size_t need_fp32 =
      ((size_t)2 * TOKENS * NE + part_elems) * sizeof(float);  // ~17 MB

  if (ws_size == 0 || ws_size >= need_mfma) {
    us* bws = (us*)d_ws;
    float* hp = (float*)(bws + bws_shorts);
    float* imp_part = hp + (size_t)2 * TOKENS * NE;
    float* load_part = imp_part + (size_t)GBLOCKS * NE;
    hipLaunchKernelGGL(prep_w1_kernel, dim3(128), dim3(256), 0, stream, w1,
                       bws);
    hipLaunchKernelGGL((gemm_mfma_kernel<2>), dim3((TOKENS / TMM) * 2),
                       dim3(256), 0, stream, x, bws, hp);
    hipLaunchKernelGGL((gate_kernel<2>), dim3(GBLOCKS), dim3(256), 0, stream,
                       hp, w2, noise, out, out + TOKENS, imp_part, load_part);
    hipLaunchKernelGGL(finalize_kernel, dim3(1), dim3(1024), 0, stream,
                       imp_part, load_part, out);
  } else if (ws_size >= need_fp32) {
    float* hp = (float*)d_ws;
    float* imp_part = hp + (size_t)2 * TOKENS * NE;
    float* load_part = imp_part + (size_t)GBLOCKS * NE;
    hipLaunchKernelGGL((gemm_fp32_kernel<2>), dim3((TOKENS / TM) * 2),
                       dim3(256), 0, stream, x, w1, hp);
    hipLaunchKernelGGL((gate_kernel<2>), dim3(GBLOCKS), dim3(256), 0, stream,
                       hp, w2, noise, out, out + TOKENS, imp_part, load_part);
    hipLaunchKernelGGL(finalize_kernel, dim3(1), dim3(1024), 0, stream,
                       imp_part, load_part, out);
  }
}